// Round 14
// baseline (95.807 us; speedup 1.0000x reference)
//
#include <hip/hip_runtime.h>
#include <cstdint>

typedef __bf16 bf16x8 __attribute__((ext_vector_type(8)));
typedef float floatx4 __attribute__((ext_vector_type(4)));

// M = 4096 rows, C(K) = 256. ROUND 14: in-kernel L2 prefetch phase.
// Sizing correction: staged operands total only 4 MB (Xs 2 MB + Ys 2 MB),
// yet R10 measured 41 MB/rep fetched beyond L2 -> 10x re-fetch from L2
// thrash (per-XCD instantaneous demand ~10 MB > 4 MB L2) at dependent-load
// latency. Cold/thrash single-pass state is the ~40 us (probe steady state
// 15.4 us is never reached in one pass; XOR-sink streaming of the SAME
// demand runs at 4.6 us chip-wide, R7).
// Fix: each block first touches 1 dword per 128B line of its A (32 KB) and
// B (128 KB) panels -- 5 dependency-free loads/thread, asm-sunk -- so the
// panels stream into L2 at full MLP; the 4-set K-loop then runs L2-hot
// (hits or MSHR-merges). No mapping assumptions, no atomics, no barriers.
// K-loop / epilogue / combine / transpose: byte-identical to verified R13.
//
// Staged layout: Xs[rb(32)][s(4)][kk(2)][rowhi(8)][quad(4)][rowlo(16)][8 bf16]
// holding X[row = rb*128+rowhi*16+rowlo][k = s*64+kk*32+quad*8+j].
// Fragment for 16-row group rowhi at K-step (s,kk): lane reads 16 B at
//   Xs + rb*32768 + (s*1024 + kk*512 + rowhi*64 + lane)*8.

#define OFF_X     (0u)
#define OFF_Y     (2u*1024*1024)
#define OFF_PMAX  (4u*1024*1024)
#define OFF_PSUM  (5u*1024*1024)
#define OFF_DIAG  (6u*1024*1024)
#define OFF_LPART (OFF_DIAG + 16384u)
#define OFF_CPART (OFF_LPART + 256u)
#define OFF_CNT   (OFF_CPART + 256u)   // cnt[0]: combine arrival counter

// ---------------------------------------------------------------------------
// K0: fp32 -> staged bf16 (verified, unchanged). Block 0 zeroes cnt.
// ---------------------------------------------------------------------------
__global__ __launch_bounds__(256) void transpose_stage(
    const float* __restrict__ pred, const float* __restrict__ gt,
    unsigned short* __restrict__ Xs, unsigned short* __restrict__ Ys,
    int* __restrict__ cnt) {
  int blk = blockIdx.x;
  const int t = threadIdx.x;
  if (blk == 0 && t < 33) cnt[t] = 0;
  const float* src;
  unsigned short* dst;
  int slab;
  if (blk < 256) { src = pred; dst = Xs; slab = blk; }
  else           { src = gt;   dst = Ys; slab = blk - 256; }
  const float* sb = src + slab * 4096;
  const int rb = slab >> 3, rowhi = slab & 7;
  #pragma unroll
  for (int half = 0; half < 2; ++half) {
    int c_ = half * 256 + t;
    int rowlo = c_ & 15;
    int quad  = (c_ >> 4) & 3;
    int kk    = (c_ >> 6) & 1;
    int s     = c_ >> 7;
    int k0 = s * 64 + kk * 32 + quad * 8;
    unsigned int packed[4];
    #pragma unroll
    for (int jj = 0; jj < 4; ++jj) {
      unsigned int lohi[2];
      #pragma unroll
      for (int e = 0; e < 2; ++e) {
        float f = sb[(k0 + jj * 2 + e) * 16 + rowlo];
        unsigned int u = __float_as_uint(f);
        lohi[e] = (u + 0x7FFFu + ((u >> 16) & 1u)) >> 16;   // RNE -> bf16
      }
      packed[jj] = lohi[0] | (lohi[1] << 16);
    }
    unsigned short* o = dst + rb * 32768 +
        (unsigned)(s * 1024 + kk * 512 + rowhi * 64 + quad * 16 + rowlo) * 8;
    uint4 v; v.x = packed[0]; v.y = packed[1]; v.z = packed[2]; v.w = packed[3];
    *reinterpret_cast<uint4*>(o) = v;
  }
}

#define KOFF(KS) ((unsigned)((((KS) >> 1) * 1024 + ((KS)&1) * 512)) * 8)

#define LOADF(AR, BR, KS) do {                                               \
    _Pragma("unroll") for (int fr = 0; fr < 4; ++fr)                         \
      AR[fr] = *reinterpret_cast<const bf16x8*>(                             \
          Ab + KOFF(KS) + (unsigned)((hh * 4 + fr) * 64) * 8);               \
    _Pragma("unroll") for (int fc = 0; fc < 4; ++fc)                         \
      BR[fc] = *reinterpret_cast<const bf16x8*>(                             \
          Bb + KOFF(KS) + (unsigned)((ch * 4 + fc) * 64) * 8);               \
  } while (0)

#define MM(AR, BR) do {                                                      \
    _Pragma("unroll") for (int fr = 0; fr < 4; ++fr)                         \
      _Pragma("unroll") for (int fc = 0; fc < 4; ++fc)                       \
        acc[fr][fc] = __builtin_amdgcn_mfma_f32_16x16x32_bf16(               \
            AR[fr], BR[fc], acc[fr][fc], 0, 0, 0);                           \
  } while (0)

#define KLOOP_PIPE4() do {                                                   \
    bf16x8 A0[4], B0[4], A1[4], B1[4], A2[4], B2[4], A3[4], B3[4];           \
    LOADF(A0, B0, 0); LOADF(A1, B1, 1);                                      \
    LOADF(A2, B2, 2); LOADF(A3, B3, 3);                                      \
    MM(A0, B0); LOADF(A0, B0, 4);                                            \
    MM(A1, B1); LOADF(A1, B1, 5);                                            \
    MM(A2, B2); LOADF(A2, B2, 6);                                            \
    MM(A3, B3); LOADF(A3, B3, 7);                                            \
    MM(A0, B0); MM(A1, B1); MM(A2, B2); MM(A3, B3);                          \
  } while (0)

// ---------------------------------------------------------------------------
// K1: per-wave 64x64 GEMM tile, no LDS, no barriers; L2-prefetch phase +
// 4-set pipelined K-loop. Static b&7 mapping (best measured).
// ---------------------------------------------------------------------------
__global__ __launch_bounds__(256, 2) void gemm_wave6(
    const unsigned short* __restrict__ Xs, const unsigned short* __restrict__ Ys,
    float* __restrict__ pmax, float* __restrict__ psum, float* __restrict__ diag) {
  const int t = threadIdx.x;
  const int wv = t >> 6, lane = t & 63;
  const int b = blockIdx.x;
  const int xcd = b & 7, slot = b >> 3;             // slot 0..127
  const int rowb = ((xcd >> 1) << 4) | (slot & 15); // 0..63 (64-row tiles)
  const int colb = ((xcd & 1) << 3) | (slot >> 4);  // 0..15 (256-col groups)
  const int hh = rowb & 1, ch = wv & 1;

  // ---- Phase 0: L2 prefetch (1 dword per 128B line, zero consumers). ----
  // A panel: 8 segments of 4KB: seg (s8 = t>>5) at shorts
  //   (rowb>>1)*32768 + (s8>>1)*8192 + (s8&1)*4096 + hh*2048; 32 thr/seg,
  //   each touches 64 shorts (128B) at (t&31)*64.
  // B panel: 128KB contiguous at (colb*2)*32768 shorts; thread t touches 4
  //   lines at t*256 + j*64 shorts.
  {
    const int s8 = t >> 5;
    const unsigned aoff = (unsigned)((rowb >> 1) * 32768 + (s8 >> 1) * 8192 +
                                     (s8 & 1) * 4096 + hh * 2048 +
                                     (t & 31) * 64);
    int sA = *reinterpret_cast<const int*>(Xs + aoff);
    const unsigned boff = (unsigned)((colb * 2) * 32768 + t * 256);
    int sB0 = *reinterpret_cast<const int*>(Ys + boff);
    int sB1 = *reinterpret_cast<const int*>(Ys + boff + 64);
    int sB2 = *reinterpret_cast<const int*>(Ys + boff + 128);
    int sB3 = *reinterpret_cast<const int*>(Ys + boff + 192);
    asm volatile("" :: "v"(sA), "v"(sB0), "v"(sB1), "v"(sB2), "v"(sB3));
  }

  const unsigned short* Ab = Xs + (rowb >> 1) * 32768 + (unsigned)lane * 8;
  const unsigned short* Bb = Ys + ((colb << 1) | (wv >> 1)) * 32768 +
                             (unsigned)lane * 8;

  floatx4 acc[4][4];
  const floatx4 zero = {0.f, 0.f, 0.f, 0.f};
  #pragma unroll
  for (int i = 0; i < 4; ++i)
    #pragma unroll
    for (int j = 0; j < 4; ++j) acc[i][j] = zero;

  KLOOP_PIPE4();

  const int quad = lane >> 4, lc = lane & 15;

  // Diagonal: wave is on the diagonal iff colb*4 + wv == rowb.
  if (colb * 4 + wv == rowb) {
    #pragma unroll
    for (int fr = 0; fr < 4; ++fr)
      #pragma unroll
      for (int r = 0; r < 4; ++r)
        if (lc == quad * 4 + r)
          diag[rowb * 64 + fr * 16 + lc] = acc[fr][fr][r];
  }

  // Per-row partials over this wave's 64 cols.
  #pragma unroll
  for (int fr = 0; fr < 4; ++fr) {
    #pragma unroll
    for (int r = 0; r < 4; ++r) {
      float v0 = acc[fr][0][r], v1 = acc[fr][1][r];
      float v2 = acc[fr][2][r], v3 = acc[fr][3][r];
      float m = fmaxf(fmaxf(v0, v1), fmaxf(v2, v3));
      #pragma unroll
      for (int sh = 1; sh < 16; sh <<= 1) m = fmaxf(m, __shfl_xor(m, sh, 64));
      float ss = __expf(v0 - m) + __expf(v1 - m) +
                 __expf(v2 - m) + __expf(v3 - m);
      #pragma unroll
      for (int sh = 1; sh < 16; sh <<= 1) ss += __shfl_xor(ss, sh, 64);
      if (lc == 0) {
        int grow = rowb * 64 + fr * 16 + quad * 4 + r;
        int p = grow * 64 + colb * 4 + wv;
        pmax[p] = m; psum[p] = ss;
      }
    }
  }
}

// ---------------------------------------------------------------------------
// K2: per-row combine + fused finalize (verified, unchanged).
// ---------------------------------------------------------------------------
__global__ __launch_bounds__(256) void combine_rows(
    const float* __restrict__ pmax, const float* __restrict__ psum,
    const float* __restrict__ diag,
    float* __restrict__ lpart, float* __restrict__ cpart,
    int* __restrict__ cnt, float* __restrict__ out) {
  int row = blockIdx.x * 256 + threadIdx.x;
  const float* pm = pmax + row * 64;
  const float* ps = psum + row * 64;
  float M = -3.4e38f;
  #pragma unroll 8
  for (int b = 0; b < 64; ++b) M = fmaxf(M, pm[b]);
  float S = 0.f;
  #pragma unroll 8
  for (int b = 0; b < 64; ++b) S += ps[b] * __expf(pm[b] - M);
  float d = diag[row];
  float lossr = logf(S) + M - d;
  float corr = (d == M) ? 1.f : 0.f;
  #pragma unroll
  for (int sh = 1; sh < 64; sh <<= 1) {
    lossr += __shfl_xor(lossr, sh, 64);
    corr  += __shfl_xor(corr,  sh, 64);
  }
  __shared__ float ls[4], cs[4];
  int wave = threadIdx.x >> 6, lane = threadIdx.x & 63;
  if (lane == 0) { ls[wave] = lossr; cs[wave] = corr; }
  __syncthreads();
  if (threadIdx.x == 0) {
    lpart[blockIdx.x] = ls[0] + ls[1] + ls[2] + ls[3];
    cpart[blockIdx.x] = cs[0] + cs[1] + cs[2] + cs[3];
    __threadfence();                     // release per-block partial
    if (atomicAdd(cnt, 1) == 15) {       // last arriver finalizes
      __threadfence();                   // acquire all partials
      float L = 0.f, C = 0.f;
      for (int i = 0; i < 16; ++i) { L += lpart[i]; C += cpart[i]; }
      out[0] = L * (1.f / 4096.f);
      out[1] = C * (100.f / 4096.f);
    }
  }
}

extern "C" void kernel_launch(void* const* d_in, const int* in_sizes, int n_in,
                              void* d_out, int out_size, void* d_ws, size_t ws_size,
                              hipStream_t stream) {
  const float* pred = (const float*)d_in[0];
  const float* gt   = (const float*)d_in[1];
  char* w = (char*)d_ws;
  unsigned short* Xbf = (unsigned short*)(w + OFF_X);
  unsigned short* Ybf = (unsigned short*)(w + OFF_Y);
  float* pmax  = (float*)(w + OFF_PMAX);
  float* psum  = (float*)(w + OFF_PSUM);
  float* diag  = (float*)(w + OFF_DIAG);
  float* lpart = (float*)(w + OFF_LPART);
  float* cpart = (float*)(w + OFF_CPART);
  int*   cnt   = (int*)(w + OFF_CNT);
  float* out   = (float*)d_out;

  transpose_stage<<<512, 256, 0, stream>>>(pred, gt, Xbf, Ybf, cnt);
  gemm_wave6<<<1024, 256, 0, stream>>>(Xbf, Ybf, pmax, psum, diag);
  combine_rows<<<16, 256, 0, stream>>>(pmax, psum, diag, lpart, cpart, cnt, out);
}

// Round 15
// 84.318 us; speedup vs baseline: 1.1363x; 1.1363x over previous
//
#include <hip/hip_runtime.h>
#include <cstdint>

typedef __bf16 bf16x8 __attribute__((ext_vector_type(8)));
typedef float floatx4 __attribute__((ext_vector_type(4)));

// M = 4096 rows, C(K) = 256. ROUND 15: coalesced partial stores.
// R13 (best, 90.85): gemm ~41 us. Accounting: warm K-loop 15.4 (R10,
// fetch-bound), epilogue compute <=3.5 (R10 probe), missing ~20 us.
// Last unvaried term: the partial stores -- 64 scattered 4B stores/wave
// (4 lines touched per instr, 2 arrays) -> write-allocate misses on every
// line, ~16x line-traffic amplification. R5 cross-check: plain coalesced
// C-stores (64 MB!) decomposed FASTER (~30-34) than the fused-partial 41.
// Fix: pmax/psum interleaved as float2 pp[cg][row] -- per (fr,r) the wave's
// 4 stores pack into ONE 128B line (8B x 32B-stride), half the instructions.
// Combine reads pp[cg*4096+row]: 256 consecutive rows/instr = coalesced.
// Everything else byte-identical to R13 (4-set pipelined K-loop, static b&7
// mapping, no LDS, no barriers, 16-fence fused finalize).
//
// Staged layout: Xs[rb(32)][s(4)][kk(2)][rowhi(8)][quad(4)][rowlo(16)][8 bf16]
// holding X[row = rb*128+rowhi*16+rowlo][k = s*64+kk*32+quad*8+j].
// Fragment for 16-row group rowhi at K-step (s,kk): lane reads 16 B at
//   Xs + rb*32768 + (s*1024 + kk*512 + rowhi*64 + lane)*8.

#define OFF_X     (0u)
#define OFF_Y     (2u*1024*1024)
#define OFF_PP    (4u*1024*1024)       // float2 pp[64 cg][4096 rows] = 2 MB
#define OFF_DIAG  (6u*1024*1024)
#define OFF_LPART (OFF_DIAG + 16384u)
#define OFF_CPART (OFF_LPART + 256u)
#define OFF_CNT   (OFF_CPART + 256u)   // cnt[0]: combine arrival counter

// ---------------------------------------------------------------------------
// K0: fp32 -> staged bf16 (verified, unchanged). Block 0 zeroes cnt.
// ---------------------------------------------------------------------------
__global__ __launch_bounds__(256) void transpose_stage(
    const float* __restrict__ pred, const float* __restrict__ gt,
    unsigned short* __restrict__ Xs, unsigned short* __restrict__ Ys,
    int* __restrict__ cnt) {
  int blk = blockIdx.x;
  const int t = threadIdx.x;
  if (blk == 0 && t < 33) cnt[t] = 0;
  const float* src;
  unsigned short* dst;
  int slab;
  if (blk < 256) { src = pred; dst = Xs; slab = blk; }
  else           { src = gt;   dst = Ys; slab = blk - 256; }
  const float* sb = src + slab * 4096;
  const int rb = slab >> 3, rowhi = slab & 7;
  #pragma unroll
  for (int half = 0; half < 2; ++half) {
    int c_ = half * 256 + t;
    int rowlo = c_ & 15;
    int quad  = (c_ >> 4) & 3;
    int kk    = (c_ >> 6) & 1;
    int s     = c_ >> 7;
    int k0 = s * 64 + kk * 32 + quad * 8;
    unsigned int packed[4];
    #pragma unroll
    for (int jj = 0; jj < 4; ++jj) {
      unsigned int lohi[2];
      #pragma unroll
      for (int e = 0; e < 2; ++e) {
        float f = sb[(k0 + jj * 2 + e) * 16 + rowlo];
        unsigned int u = __float_as_uint(f);
        lohi[e] = (u + 0x7FFFu + ((u >> 16) & 1u)) >> 16;   // RNE -> bf16
      }
      packed[jj] = lohi[0] | (lohi[1] << 16);
    }
    unsigned short* o = dst + rb * 32768 +
        (unsigned)(s * 1024 + kk * 512 + rowhi * 64 + quad * 16 + rowlo) * 8;
    uint4 v; v.x = packed[0]; v.y = packed[1]; v.z = packed[2]; v.w = packed[3];
    *reinterpret_cast<uint4*>(o) = v;
  }
}

#define KOFF(KS) ((unsigned)((((KS) >> 1) * 1024 + ((KS)&1) * 512)) * 8)

#define LOADF(AR, BR, KS) do {                                               \
    _Pragma("unroll") for (int fr = 0; fr < 4; ++fr)                         \
      AR[fr] = *reinterpret_cast<const bf16x8*>(                             \
          Ab + KOFF(KS) + (unsigned)((hh * 4 + fr) * 64) * 8);               \
    _Pragma("unroll") for (int fc = 0; fc < 4; ++fc)                         \
      BR[fc] = *reinterpret_cast<const bf16x8*>(                             \
          Bb + KOFF(KS) + (unsigned)((ch * 4 + fc) * 64) * 8);               \
  } while (0)

#define MM(AR, BR) do {                                                      \
    _Pragma("unroll") for (int fr = 0; fr < 4; ++fr)                         \
      _Pragma("unroll") for (int fc = 0; fc < 4; ++fc)                       \
        acc[fr][fc] = __builtin_amdgcn_mfma_f32_16x16x32_bf16(               \
            AR[fr], BR[fc], acc[fr][fc], 0, 0, 0);                           \
  } while (0)

#define KLOOP_PIPE4() do {                                                   \
    bf16x8 A0[4], B0[4], A1[4], B1[4], A2[4], B2[4], A3[4], B3[4];           \
    LOADF(A0, B0, 0); LOADF(A1, B1, 1);                                      \
    LOADF(A2, B2, 2); LOADF(A3, B3, 3);                                      \
    MM(A0, B0); LOADF(A0, B0, 4);                                            \
    MM(A1, B1); LOADF(A1, B1, 5);                                            \
    MM(A2, B2); LOADF(A2, B2, 6);                                            \
    MM(A3, B3); LOADF(A3, B3, 7);                                            \
    MM(A0, B0); MM(A1, B1); MM(A2, B2); MM(A3, B3);                          \
  } while (0)

// ---------------------------------------------------------------------------
// K1: per-wave 64x64 GEMM tile, no LDS, no barriers, 4-set pipelined loads,
// static b&7 mapping. Epilogue: per-row (max,sum-exp) partials stored as
// ONE float2 per (row, colgroup) -> 1 cache line per (fr,r) per wave.
// ---------------------------------------------------------------------------
__global__ __launch_bounds__(256, 2) void gemm_wave7(
    const unsigned short* __restrict__ Xs, const unsigned short* __restrict__ Ys,
    float2* __restrict__ pp, float* __restrict__ diag) {
  const int t = threadIdx.x;
  const int wv = t >> 6, lane = t & 63;
  const int b = blockIdx.x;
  const int xcd = b & 7, slot = b >> 3;             // slot 0..127
  const int rowb = ((xcd >> 1) << 4) | (slot & 15); // 0..63 (64-row tiles)
  const int colb = ((xcd & 1) << 3) | (slot >> 4);  // 0..15 (256-col groups)
  const int hh = rowb & 1, ch = wv & 1;
  const unsigned short* Ab = Xs + (rowb >> 1) * 32768 + (unsigned)lane * 8;
  const unsigned short* Bb = Ys + ((colb << 1) | (wv >> 1)) * 32768 +
                             (unsigned)lane * 8;

  floatx4 acc[4][4];
  const floatx4 zero = {0.f, 0.f, 0.f, 0.f};
  #pragma unroll
  for (int i = 0; i < 4; ++i)
    #pragma unroll
    for (int j = 0; j < 4; ++j) acc[i][j] = zero;

  KLOOP_PIPE4();

  const int quad = lane >> 4, lc = lane & 15;

  // Diagonal: wave is on the diagonal iff colb*4 + wv == rowb.
  if (colb * 4 + wv == rowb) {
    #pragma unroll
    for (int fr = 0; fr < 4; ++fr)
      #pragma unroll
      for (int r = 0; r < 4; ++r)
        if (lc == quad * 4 + r)
          diag[rowb * 64 + fr * 16 + lc] = acc[fr][fr][r];
  }

  // Per-row partials over this wave's 64 cols; one float2 store per (fr,r)
  // per quad: addresses for the 4 quads are 32 B apart -> single 128 B line.
  const int cg = colb * 4 + wv;                      // col-group 0..63
  #pragma unroll
  for (int fr = 0; fr < 4; ++fr) {
    #pragma unroll
    for (int r = 0; r < 4; ++r) {
      float v0 = acc[fr][0][r], v1 = acc[fr][1][r];
      float v2 = acc[fr][2][r], v3 = acc[fr][3][r];
      float m = fmaxf(fmaxf(v0, v1), fmaxf(v2, v3));
      #pragma unroll
      for (int sh = 1; sh < 16; sh <<= 1) m = fmaxf(m, __shfl_xor(m, sh, 64));
      float ss = __expf(v0 - m) + __expf(v1 - m) +
                 __expf(v2 - m) + __expf(v3 - m);
      #pragma unroll
      for (int sh = 1; sh < 16; sh <<= 1) ss += __shfl_xor(ss, sh, 64);
      if (lc == 0) {
        int grow = rowb * 64 + fr * 16 + quad * 4 + r;
        pp[cg * 4096 + grow] = make_float2(m, ss);
      }
    }
  }
}

// ---------------------------------------------------------------------------
// K2: per-row combine of 64 float2 partials (coalesced: 256 consecutive
// rows per load instr) + fused finalize (16 fences, verified).
// ---------------------------------------------------------------------------
__global__ __launch_bounds__(256) void combine_rows(
    const float2* __restrict__ pp, const float* __restrict__ diag,
    float* __restrict__ lpart, float* __restrict__ cpart,
    int* __restrict__ cnt, float* __restrict__ out) {
  int row = blockIdx.x * 256 + threadIdx.x;
  float2 v[64];
  #pragma unroll
  for (int cg = 0; cg < 64; ++cg) v[cg] = pp[cg * 4096 + row];
  float M = -3.4e38f;
  #pragma unroll
  for (int cg = 0; cg < 64; ++cg) M = fmaxf(M, v[cg].x);
  float S = 0.f;
  #pragma unroll
  for (int cg = 0; cg < 64; ++cg) S += v[cg].y * __expf(v[cg].x - M);
  float d = diag[row];
  float lossr = logf(S) + M - d;
  float corr = (d == M) ? 1.f : 0.f;
  #pragma unroll
  for (int sh = 1; sh < 64; sh <<= 1) {
    lossr += __shfl_xor(lossr, sh, 64);
    corr  += __shfl_xor(corr,  sh, 64);
  }
  __shared__ float ls[4], cs[4];
  int wave = threadIdx.x >> 6, lane = threadIdx.x & 63;
  if (lane == 0) { ls[wave] = lossr; cs[wave] = corr; }
  __syncthreads();
  if (threadIdx.x == 0) {
    lpart[blockIdx.x] = ls[0] + ls[1] + ls[2] + ls[3];
    cpart[blockIdx.x] = cs[0] + cs[1] + cs[2] + cs[3];
    __threadfence();                     // release per-block partial
    if (atomicAdd(cnt, 1) == 15) {       // last arriver finalizes
      __threadfence();                   // acquire all partials
      float L = 0.f, C = 0.f;
      for (int i = 0; i < 16; ++i) { L += lpart[i]; C += cpart[i]; }
      out[0] = L * (1.f / 4096.f);
      out[1] = C * (100.f / 4096.f);
    }
  }
}

extern "C" void kernel_launch(void* const* d_in, const int* in_sizes, int n_in,
                              void* d_out, int out_size, void* d_ws, size_t ws_size,
                              hipStream_t stream) {
  const float* pred = (const float*)d_in[0];
  const float* gt   = (const float*)d_in[1];
  char* w = (char*)d_ws;
  unsigned short* Xbf = (unsigned short*)(w + OFF_X);
  unsigned short* Ybf = (unsigned short*)(w + OFF_Y);
  float2* pp   = (float2*)(w + OFF_PP);
  float* diag  = (float*)(w + OFF_DIAG);
  float* lpart = (float*)(w + OFF_LPART);
  float* cpart = (float*)(w + OFF_CPART);
  int*   cnt   = (int*)(w + OFF_CNT);
  float* out   = (float*)d_out;

  transpose_stage<<<512, 256, 0, stream>>>(pred, gt, Xbf, Ybf, cnt);
  gemm_wave7<<<1024, 256, 0, stream>>>(Xbf, Ybf, pp, diag);
  combine_rows<<<16, 256, 0, stream>>>(pp, diag, lpart, cpart, cnt, out);
}

// Round 16
// 83.708 us; speedup vs baseline: 1.1445x; 1.0073x over previous
//
#include <hip/hip_runtime.h>
#include <cstdint>

typedef __bf16 bf16x8 __attribute__((ext_vector_type(8)));
typedef float floatx4 __attribute__((ext_vector_type(4)));

// M = 4096 rows, C(K) = 256. ROUND 16: colb-major sweep (A-resident).
// R15 (best, 84.3): coalesced float2 partial stores recovered 6.5 us; G~34.
// R10's 41 MB/rep fetch now closes arithmetically against R13/R15's block
// order: colb advanced every 128 blocks -> ALL 64 A panels re-swept per
// colb-phase (8 phases x ~3 MB scattered A + 16 MB B ~= 40 MB). Fix (one
// line): b = colb*64 + rowb (rowb = b&63, colb = b>>6). Consecutive blocks
// share one colb; under round-robin dispatch each XCD sees only rowb == id
// (mod 8) -> A resident at 256 KB/XCD fetched once; B swept once per XCD.
// Ideal fetch 18 MB, worst case ~48 (no regression path).
// Everything else byte-identical to R15 (4-set pipelined K-loop, float2
// pp stores, 16-fence fused finalize).
//
// Staged layout: Xs[rb(32)][s(4)][kk(2)][rowhi(8)][quad(4)][rowlo(16)][8 bf16]
// holding X[row = rb*128+rowhi*16+rowlo][k = s*64+kk*32+quad*8+j].
// Fragment for 16-row group rowhi at K-step (s,kk): lane reads 16 B at
//   Xs + rb*32768 + (s*1024 + kk*512 + rowhi*64 + lane)*8.

#define OFF_X     (0u)
#define OFF_Y     (2u*1024*1024)
#define OFF_PP    (4u*1024*1024)       // float2 pp[64 cg][4096 rows] = 2 MB
#define OFF_DIAG  (6u*1024*1024)
#define OFF_LPART (OFF_DIAG + 16384u)
#define OFF_CPART (OFF_LPART + 256u)
#define OFF_CNT   (OFF_CPART + 256u)   // cnt[0]: combine arrival counter

// ---------------------------------------------------------------------------
// K0: fp32 -> staged bf16 (verified, unchanged). Block 0 zeroes cnt.
// ---------------------------------------------------------------------------
__global__ __launch_bounds__(256) void transpose_stage(
    const float* __restrict__ pred, const float* __restrict__ gt,
    unsigned short* __restrict__ Xs, unsigned short* __restrict__ Ys,
    int* __restrict__ cnt) {
  int blk = blockIdx.x;
  const int t = threadIdx.x;
  if (blk == 0 && t < 33) cnt[t] = 0;
  const float* src;
  unsigned short* dst;
  int slab;
  if (blk < 256) { src = pred; dst = Xs; slab = blk; }
  else           { src = gt;   dst = Ys; slab = blk - 256; }
  const float* sb = src + slab * 4096;
  const int rb = slab >> 3, rowhi = slab & 7;
  #pragma unroll
  for (int half = 0; half < 2; ++half) {
    int c_ = half * 256 + t;
    int rowlo = c_ & 15;
    int quad  = (c_ >> 4) & 3;
    int kk    = (c_ >> 6) & 1;
    int s     = c_ >> 7;
    int k0 = s * 64 + kk * 32 + quad * 8;
    unsigned int packed[4];
    #pragma unroll
    for (int jj = 0; jj < 4; ++jj) {
      unsigned int lohi[2];
      #pragma unroll
      for (int e = 0; e < 2; ++e) {
        float f = sb[(k0 + jj * 2 + e) * 16 + rowlo];
        unsigned int u = __float_as_uint(f);
        lohi[e] = (u + 0x7FFFu + ((u >> 16) & 1u)) >> 16;   // RNE -> bf16
      }
      packed[jj] = lohi[0] | (lohi[1] << 16);
    }
    unsigned short* o = dst + rb * 32768 +
        (unsigned)(s * 1024 + kk * 512 + rowhi * 64 + quad * 16 + rowlo) * 8;
    uint4 v; v.x = packed[0]; v.y = packed[1]; v.z = packed[2]; v.w = packed[3];
    *reinterpret_cast<uint4*>(o) = v;
  }
}

#define KOFF(KS) ((unsigned)((((KS) >> 1) * 1024 + ((KS)&1) * 512)) * 8)

#define LOADF(AR, BR, KS) do {                                               \
    _Pragma("unroll") for (int fr = 0; fr < 4; ++fr)                         \
      AR[fr] = *reinterpret_cast<const bf16x8*>(                             \
          Ab + KOFF(KS) + (unsigned)((hh * 4 + fr) * 64) * 8);               \
    _Pragma("unroll") for (int fc = 0; fc < 4; ++fc)                         \
      BR[fc] = *reinterpret_cast<const bf16x8*>(                             \
          Bb + KOFF(KS) + (unsigned)((ch * 4 + fc) * 64) * 8);               \
  } while (0)

#define MM(AR, BR) do {                                                      \
    _Pragma("unroll") for (int fr = 0; fr < 4; ++fr)                         \
      _Pragma("unroll") for (int fc = 0; fc < 4; ++fc)                       \
        acc[fr][fc] = __builtin_amdgcn_mfma_f32_16x16x32_bf16(               \
            AR[fr], BR[fc], acc[fr][fc], 0, 0, 0);                           \
  } while (0)

#define KLOOP_PIPE4() do {                                                   \
    bf16x8 A0[4], B0[4], A1[4], B1[4], A2[4], B2[4], A3[4], B3[4];           \
    LOADF(A0, B0, 0); LOADF(A1, B1, 1);                                      \
    LOADF(A2, B2, 2); LOADF(A3, B3, 3);                                      \
    MM(A0, B0); LOADF(A0, B0, 4);                                            \
    MM(A1, B1); LOADF(A1, B1, 5);                                            \
    MM(A2, B2); LOADF(A2, B2, 6);                                            \
    MM(A3, B3); LOADF(A3, B3, 7);                                            \
    MM(A0, B0); MM(A1, B1); MM(A2, B2); MM(A3, B3);                          \
  } while (0)

// ---------------------------------------------------------------------------
// K1: per-wave 64x64 GEMM tile, no LDS, no barriers, 4-set pipelined loads.
// Block order: colb-major (b = colb*64 + rowb) -> A panels XCD-resident,
// B swept once. Epilogue: coalesced float2 pp stores (R15, verified).
// ---------------------------------------------------------------------------
__global__ __launch_bounds__(256, 2) void gemm_wave8(
    const unsigned short* __restrict__ Xs, const unsigned short* __restrict__ Ys,
    float2* __restrict__ pp, float* __restrict__ diag) {
  const int t = threadIdx.x;
  const int wv = t >> 6, lane = t & 63;
  const int b = blockIdx.x;
  const int rowb = b & 63;                          // 0..63 (64-row tiles)
  const int colb = b >> 6;                          // 0..15 (256-col groups)
  const int hh = rowb & 1, ch = wv & 1;
  const unsigned short* Ab = Xs + (rowb >> 1) * 32768 + (unsigned)lane * 8;
  const unsigned short* Bb = Ys + ((colb << 1) | (wv >> 1)) * 32768 +
                             (unsigned)lane * 8;

  floatx4 acc[4][4];
  const floatx4 zero = {0.f, 0.f, 0.f, 0.f};
  #pragma unroll
  for (int i = 0; i < 4; ++i)
    #pragma unroll
    for (int j = 0; j < 4; ++j) acc[i][j] = zero;

  KLOOP_PIPE4();

  const int quad = lane >> 4, lc = lane & 15;

  // Diagonal: wave is on the diagonal iff colb*4 + wv == rowb.
  if (colb * 4 + wv == rowb) {
    #pragma unroll
    for (int fr = 0; fr < 4; ++fr)
      #pragma unroll
      for (int r = 0; r < 4; ++r)
        if (lc == quad * 4 + r)
          diag[rowb * 64 + fr * 16 + lc] = acc[fr][fr][r];
  }

  // Per-row partials over this wave's 64 cols; one float2 store per (fr,r)
  // per quad: addresses for the 4 quads are 32 B apart -> single 128 B line.
  const int cg = colb * 4 + wv;                      // col-group 0..63
  #pragma unroll
  for (int fr = 0; fr < 4; ++fr) {
    #pragma unroll
    for (int r = 0; r < 4; ++r) {
      float v0 = acc[fr][0][r], v1 = acc[fr][1][r];
      float v2 = acc[fr][2][r], v3 = acc[fr][3][r];
      float m = fmaxf(fmaxf(v0, v1), fmaxf(v2, v3));
      #pragma unroll
      for (int sh = 1; sh < 16; sh <<= 1) m = fmaxf(m, __shfl_xor(m, sh, 64));
      float ss = __expf(v0 - m) + __expf(v1 - m) +
                 __expf(v2 - m) + __expf(v3 - m);
      #pragma unroll
      for (int sh = 1; sh < 16; sh <<= 1) ss += __shfl_xor(ss, sh, 64);
      if (lc == 0) {
        int grow = rowb * 64 + fr * 16 + quad * 4 + r;
        pp[cg * 4096 + grow] = make_float2(m, ss);
      }
    }
  }
}

// ---------------------------------------------------------------------------
// K2: per-row combine of 64 float2 partials (coalesced) + fused finalize
// (16 fences, verified).
// ---------------------------------------------------------------------------
__global__ __launch_bounds__(256) void combine_rows(
    const float2* __restrict__ pp, const float* __restrict__ diag,
    float* __restrict__ lpart, float* __restrict__ cpart,
    int* __restrict__ cnt, float* __restrict__ out) {
  int row = blockIdx.x * 256 + threadIdx.x;
  float2 v[64];
  #pragma unroll
  for (int cg = 0; cg < 64; ++cg) v[cg] = pp[cg * 4096 + row];
  float M = -3.4e38f;
  #pragma unroll
  for (int cg = 0; cg < 64; ++cg) M = fmaxf(M, v[cg].x);
  float S = 0.f;
  #pragma unroll
  for (int cg = 0; cg < 64; ++cg) S += v[cg].y * __expf(v[cg].x - M);
  float d = diag[row];
  float lossr = logf(S) + M - d;
  float corr = (d == M) ? 1.f : 0.f;
  #pragma unroll
  for (int sh = 1; sh < 64; sh <<= 1) {
    lossr += __shfl_xor(lossr, sh, 64);
    corr  += __shfl_xor(corr,  sh, 64);
  }
  __shared__ float ls[4], cs[4];
  int wave = threadIdx.x >> 6, lane = threadIdx.x & 63;
  if (lane == 0) { ls[wave] = lossr; cs[wave] = corr; }
  __syncthreads();
  if (threadIdx.x == 0) {
    lpart[blockIdx.x] = ls[0] + ls[1] + ls[2] + ls[3];
    cpart[blockIdx.x] = cs[0] + cs[1] + cs[2] + cs[3];
    __threadfence();                     // release per-block partial
    if (atomicAdd(cnt, 1) == 15) {       // last arriver finalizes
      __threadfence();                   // acquire all partials
      float L = 0.f, C = 0.f;
      for (int i = 0; i < 16; ++i) { L += lpart[i]; C += cpart[i]; }
      out[0] = L * (1.f / 4096.f);
      out[1] = C * (100.f / 4096.f);
    }
  }
}

extern "C" void kernel_launch(void* const* d_in, const int* in_sizes, int n_in,
                              void* d_out, int out_size, void* d_ws, size_t ws_size,
                              hipStream_t stream) {
  const float* pred = (const float*)d_in[0];
  const float* gt   = (const float*)d_in[1];
  char* w = (char*)d_ws;
  unsigned short* Xbf = (unsigned short*)(w + OFF_X);
  unsigned short* Ybf = (unsigned short*)(w + OFF_Y);
  float2* pp   = (float2*)(w + OFF_PP);
  float* diag  = (float*)(w + OFF_DIAG);
  float* lpart = (float*)(w + OFF_LPART);
  float* cpart = (float*)(w + OFF_CPART);
  int*   cnt   = (int*)(w + OFF_CNT);
  float* out   = (float*)d_out;

  transpose_stage<<<512, 256, 0, stream>>>(pred, gt, Xbf, Ybf, cnt);
  gemm_wave8<<<1024, 256, 0, stream>>>(Xbf, Ybf, pp, diag);
  combine_rows<<<16, 256, 0, stream>>>(pp, diag, lpart, cpart, cnt, out);
}